// Round 1
// baseline (386.082 us; speedup 1.0000x reference)
//
#include <hip/hip_runtime.h>
#include <hip/hip_bf16.h>
#include <stdint.h>

// B=2, S=2048, D=1024, H=16, DK=64
typedef __bf16 bf16x8 __attribute__((ext_vector_type(8)));
typedef float f32x4 __attribute__((ext_vector_type(4)));

__device__ __forceinline__ void gld16(const void* g, void* l) {
  // async global->LDS, 16B/lane. LDS dest must be wave-uniform base + lane*16.
  __builtin_amdgcn_global_load_lds(
      (__attribute__((address_space(1))) void*)(uintptr_t)(g),
      (__attribute__((address_space(3))) void*)(l), 16, 0, 0);
}

// ---------------- cast f32 -> bf16 ----------------
struct CastArgs {
  const float* src[7];
  __bf16* dst[7];
  int n[7];
};

__global__ __launch_bounds__(256) void cast_bf16_kernel(CastArgs a) {
  const int t = blockIdx.y;
  const int i = (blockIdx.x * 256 + threadIdx.x) * 8;
  if (i >= a.n[t]) return;
  const float4* s = (const float4*)(a.src[t] + i);
  float4 v0 = s[0], v1 = s[1];
  bf16x8 o;
  o[0] = (__bf16)v0.x; o[1] = (__bf16)v0.y; o[2] = (__bf16)v0.z; o[3] = (__bf16)v0.w;
  o[4] = (__bf16)v1.x; o[5] = (__bf16)v1.y; o[6] = (__bf16)v1.z; o[7] = (__bf16)v1.w;
  *(bf16x8*)(a.dst[t] + i) = o;
}

// ---------------- GEMM: C[m][n] = sum_k A[m][k]*B[n][k] + bias, K=1024 ----
// MODE 0: bf16 out -> Qh/Kh layout [b][h][s][dk]  (m=b*2048+s, n=h*64+dk)
// MODE 1: bf16 out -> Vt layout [b][h][dk][s]     (m=h*64+dk [A=W], n=b*2048+s [B=X])
// MODE 2: f32 out  -> [m][n] row-major (final projection)
template <int MODE>
__global__ __launch_bounds__(256) void gemm_bt(const __bf16* __restrict__ A,
                                               const __bf16* __restrict__ B,
                                               const float* __restrict__ bias,
                                               void* __restrict__ outp) {
  __shared__ __align__(16) __bf16 As[128 * 32];
  __shared__ __align__(16) __bf16 Bs[128 * 32];
  const int tid = threadIdx.x;
  const int m0 = blockIdx.y * 128;
  const int n0 = blockIdx.x * 128;
  const int lane = tid & 63, wid = tid >> 6;
  const int wm = (wid & 1) * 64, wn = (wid >> 1) * 64;
  const int l16 = lane & 15, quad = lane >> 4;

  const __bf16* ga = A + (size_t)(m0 + (tid >> 2)) * 1024 + (tid & 3) * 8;
  const __bf16* gb = B + (size_t)(n0 + (tid >> 2)) * 1024 + (tid & 3) * 8;
  char* lA = (char*)As + tid * 16;
  char* lB = (char*)Bs + tid * 16;
  const int a_off = (wm + l16) * 64 + quad * 16;  // bytes into As (row stride 64B)
  const int b_off = (wn + l16) * 64 + quad * 16;

  f32x4 acc[4][4] = {};

  for (int k0 = 0; k0 < 1024; k0 += 32) {
    __syncthreads();
    gld16(ga + k0, lA);
    gld16(ga + k0 + 64 * 1024, lA + 4096);
    gld16(gb + k0, lB);
    gld16(gb + k0 + 64 * 1024, lB + 4096);
    __syncthreads();
    bf16x8 af[4], bfr[4];
#pragma unroll
    for (int mi = 0; mi < 4; ++mi)
      af[mi] = *(const bf16x8*)((const char*)As + a_off + mi * 1024);
#pragma unroll
    for (int ni = 0; ni < 4; ++ni)
      bfr[ni] = *(const bf16x8*)((const char*)Bs + b_off + ni * 1024);
#pragma unroll
    for (int mi = 0; mi < 4; ++mi)
#pragma unroll
      for (int ni = 0; ni < 4; ++ni)
        acc[mi][ni] = __builtin_amdgcn_mfma_f32_16x16x32_bf16(af[mi], bfr[ni],
                                                              acc[mi][ni], 0, 0, 0);
  }

  if (MODE == 2) {
    float* out = (float*)outp;
#pragma unroll
    for (int ni = 0; ni < 4; ++ni) {
      const int col = n0 + wn + ni * 16 + l16;
      const float bb = bias[col];
#pragma unroll
      for (int mi = 0; mi < 4; ++mi)
#pragma unroll
        for (int r = 0; r < 4; ++r) {
          const int row = m0 + wm + mi * 16 + quad * 4 + r;
          out[(size_t)row * 1024 + col] = acc[mi][ni][r] + bb;
        }
    }
  } else if (MODE == 0) {
    __bf16* out = (__bf16*)outp;
#pragma unroll
    for (int ni = 0; ni < 4; ++ni) {
      const int col = n0 + wn + ni * 16 + l16;
      const int h = col >> 6, dk = col & 63;
      const float bb = bias[col];
#pragma unroll
      for (int mi = 0; mi < 4; ++mi)
#pragma unroll
        for (int r = 0; r < 4; ++r) {
          const int row = m0 + wm + mi * 16 + quad * 4 + r;
          const int b = row >> 11, s = row & 2047;
          out[((size_t)(b * 16 + h) * 2048 + s) * 64 + dk] =
              (__bf16)(acc[mi][ni][r] + bb);
        }
    }
  } else {  // MODE 1: A=W (m=feature), B=X (n=token); store Vt[b][h][dk][s]
    __bf16* out = (__bf16*)outp;
#pragma unroll
    for (int mi = 0; mi < 4; ++mi)
#pragma unroll
      for (int r = 0; r < 4; ++r) {
        const int rowm = m0 + wm + mi * 16 + quad * 4 + r;
        const int h = rowm >> 6, dk = rowm & 63;
        const float bb = bias[rowm];
#pragma unroll
        for (int ni = 0; ni < 4; ++ni) {
          const int coln = n0 + wn + ni * 16 + l16;
          const int b = coln >> 11, s = coln & 2047;
          out[((size_t)(b * 16 + h) * 64 + dk) * 2048 + s] =
              (__bf16)(acc[mi][ni][r] + bb);
        }
      }
  }
}

// ---------------- flash attention with post-softmax group scaling ---------
// Qh,Kh: [b][h][s][64] bf16; Vt: [b][h][64][2048] bf16; out xb: [b][s][1024] bf16
__global__ __launch_bounds__(256) void attn_kernel(
    const __bf16* __restrict__ Qh, const __bf16* __restrict__ Kh,
    const __bf16* __restrict__ Vt, const float* __restrict__ gprob,
    const int* __restrict__ maskp, __bf16* __restrict__ xb) {
  __shared__ __align__(16) __bf16 Qs[64 * 64];
  __shared__ __align__(16) __bf16 Ks[64 * 64];
  __shared__ __align__(16) __bf16 Vs[64 * 64];   // Vt tile: [dk][s_rel]
  __shared__ __align__(16) __bf16 Ps[4][16 * 64];

  const int tid = threadIdx.x;
  const int qt = blockIdx.x, bh = blockIdx.y;
  const int b = bh >> 4, h = bh & 15;
  const int q0 = qt * 64;
  const int lane = tid & 63, wid = tid >> 6, l16 = lane & 15, quad = lane >> 4;
  const size_t head_off = (size_t)bh * (2048 * 64);

  {
    const __bf16* gq = Qh + head_off + (size_t)(q0 + (tid >> 3)) * 64 + (tid & 7) * 8;
    gld16(gq, (char*)Qs + tid * 16);
    gld16(gq + 32 * 64, (char*)Qs + 4096 + tid * 16);
  }
  __syncthreads();
  bf16x8 aq[2];
  aq[0] = *(const bf16x8*)((const char*)Qs + (wid * 16 + l16) * 128 + quad * 16);
  aq[1] = *(const bf16x8*)((const char*)Qs + (wid * 16 + l16) * 128 + 64 + quad * 16);

  f32x4 o[4] = {};
  float m_row[4], l_row[4];
  int irow[4];
#pragma unroll
  for (int r = 0; r < 4; ++r) {
    m_row[r] = -__builtin_inff();
    l_row[r] = 0.f;
    irow[r] = q0 + wid * 16 + quad * 4 + r;
  }

  const __bf16* gkb = Kh + head_off;
  const __bf16* gvb = Vt + head_off;
  const int* mrow = maskp + b * 2048;
  const float* gpb = gprob + (size_t)b * 2048 * 2048;

  for (int kt = 0; kt < 32; ++kt) {
    __syncthreads();  // protect Ks/Vs from previous iteration's readers
    {
      const __bf16* gk = gkb + (size_t)(kt * 64 + (tid >> 3)) * 64 + (tid & 7) * 8;
      gld16(gk, (char*)Ks + tid * 16);
      gld16(gk + 32 * 64, (char*)Ks + 4096 + tid * 16);
      const __bf16* gv = gvb + (size_t)(tid >> 3) * 2048 + kt * 64 + (tid & 7) * 8;
      gld16(gv, (char*)Vs + tid * 16);
      gld16(gv + 32 * 2048, (char*)Vs + 4096 + tid * 16);
    }
    __syncthreads();  // includes vmcnt(0): staging landed

    // QK^T: D[m=q_rel][n=k_rel]
    f32x4 sc[4] = {};
#pragma unroll
    for (int kh = 0; kh < 2; ++kh)
#pragma unroll
      for (int ni = 0; ni < 4; ++ni) {
        bf16x8 bk = *(const bf16x8*)((const char*)Ks + (ni * 16 + l16) * 128 +
                                     kh * 64 + quad * 16);
        sc[ni] = __builtin_amdgcn_mfma_f32_16x16x32_bf16(aq[kh], bk, sc[ni], 0, 0, 0);
      }

    // scale + combined mask (mask[b,j] | (i==j))
    float sv[4][4];
#pragma unroll
    for (int ni = 0; ni < 4; ++ni) {
      const int j = kt * 64 + ni * 16 + l16;
      const int mj = mrow[j];
#pragma unroll
      for (int r = 0; r < 4; ++r) {
        const float s = sc[ni][r] * 0.125f;
        sv[ni][r] = (mj != 0 || j == irow[r]) ? s : -1e30f;
      }
    }

    // online softmax stats (rows replicated across the 16 lanes of each quad)
#pragma unroll
    for (int r = 0; r < 4; ++r) {
      float mx = fmaxf(fmaxf(sv[0][r], sv[1][r]), fmaxf(sv[2][r], sv[3][r]));
      mx = fmaxf(mx, __shfl_xor(mx, 1));
      mx = fmaxf(mx, __shfl_xor(mx, 2));
      mx = fmaxf(mx, __shfl_xor(mx, 4));
      mx = fmaxf(mx, __shfl_xor(mx, 8));
      const float mnew = fmaxf(m_row[r], mx);
      const float alpha = __expf(m_row[r] - mnew);
      float rs = 0.f;
#pragma unroll
      for (int ni = 0; ni < 4; ++ni) {
        const float p = __expf(sv[ni][r] - mnew);
        sv[ni][r] = p;
        rs += p;
      }
      rs += __shfl_xor(rs, 1);
      rs += __shfl_xor(rs, 2);
      rs += __shfl_xor(rs, 4);
      rs += __shfl_xor(rs, 8);
      l_row[r] = l_row[r] * alpha + rs;  // denominator WITHOUT group_prob
      m_row[r] = mnew;
#pragma unroll
      for (int ni = 0; ni < 4; ++ni) o[ni][r] *= alpha;
    }

    // P' = p * group_prob -> per-wave LDS tile (C-layout -> A-layout transform)
#pragma unroll
    for (int ni = 0; ni < 4; ++ni) {
      const int j = kt * 64 + ni * 16 + l16;
#pragma unroll
      for (int r = 0; r < 4; ++r) {
        const float g = gpb[(size_t)irow[r] * 2048 + j];
        Ps[wid][(quad * 4 + r) * 64 + ni * 16 + l16] = (__bf16)(sv[ni][r] * g);
      }
    }
    asm volatile("s_waitcnt lgkmcnt(0)" ::: "memory");  // wave-private write->read

    // O += P' @ V  (B-frag from transposed Vs tile is contiguous b128)
#pragma unroll
    for (int kh = 0; kh < 2; ++kh) {
      bf16x8 ap = *(const bf16x8*)((const char*)&Ps[wid][0] + l16 * 128 +
                                   kh * 64 + quad * 16);
#pragma unroll
      for (int ni = 0; ni < 4; ++ni) {
        bf16x8 bv = *(const bf16x8*)((const char*)Vs + (ni * 16 + l16) * 128 +
                                     kh * 64 + quad * 16);
        o[ni] = __builtin_amdgcn_mfma_f32_16x16x32_bf16(ap, bv, o[ni], 0, 0, 0);
      }
    }
  }

  // x[b][s][h*64+dk] = O / l
#pragma unroll
  for (int ni = 0; ni < 4; ++ni) {
    const int dk = ni * 16 + l16;
#pragma unroll
    for (int r = 0; r < 4; ++r) {
      const float val = o[ni][r] / l_row[r];
      xb[((size_t)(b * 2048 + irow[r])) * 1024 + h * 64 + dk] = (__bf16)val;
    }
  }
}

extern "C" void kernel_launch(void* const* d_in, const int* in_sizes, int n_in,
                              void* d_out, int out_size, void* d_ws, size_t ws_size,
                              hipStream_t stream) {
  const float* query = (const float*)d_in[0];
  const float* key_  = (const float*)d_in[1];
  const float* value = (const float*)d_in[2];
  const float* gprob = (const float*)d_in[3];
  const int*   maskp = (const int*)d_in[4];
  const float* Wq = (const float*)d_in[5];
  const float* bq = (const float*)d_in[6];
  const float* Wk = (const float*)d_in[7];
  const float* bk = (const float*)d_in[8];
  const float* Wv = (const float*)d_in[9];
  const float* bv = (const float*)d_in[10];
  const float* Wo = (const float*)d_in[11];
  const float* bo = (const float*)d_in[12];

  char* ws = (char*)d_ws;
  const size_t MB = 1 << 20;
  __bf16* qb  = (__bf16*)(ws + 0 * MB);
  __bf16* kb  = (__bf16*)(ws + 8 * MB);
  __bf16* vb  = (__bf16*)(ws + 16 * MB);
  __bf16* Wqb = (__bf16*)(ws + 24 * MB);
  __bf16* Wkb = (__bf16*)(ws + 26 * MB);
  __bf16* Wvb = (__bf16*)(ws + 28 * MB);
  __bf16* Wob = (__bf16*)(ws + 30 * MB);
  __bf16* Qh  = (__bf16*)(ws + 32 * MB);
  __bf16* Kh  = (__bf16*)(ws + 40 * MB);
  __bf16* Vt  = (__bf16*)(ws + 48 * MB);
  __bf16* xb  = (__bf16*)(ws + 56 * MB);

  CastArgs ca;
  ca.src[0] = query; ca.dst[0] = qb;  ca.n[0] = 4194304;
  ca.src[1] = key_;  ca.dst[1] = kb;  ca.n[1] = 4194304;
  ca.src[2] = value; ca.dst[2] = vb;  ca.n[2] = 4194304;
  ca.src[3] = Wq;    ca.dst[3] = Wqb; ca.n[3] = 1048576;
  ca.src[4] = Wk;    ca.dst[4] = Wkb; ca.n[4] = 1048576;
  ca.src[5] = Wv;    ca.dst[5] = Wvb; ca.n[5] = 1048576;
  ca.src[6] = Wo;    ca.dst[6] = Wob; ca.n[6] = 1048576;

  cast_bf16_kernel<<<dim3(2048, 7), 256, 0, stream>>>(ca);
  // Q,K projections: [4096,1024] x [1024,1024]^T -> [b][h][s][dk]
  gemm_bt<0><<<dim3(8, 32), 256, 0, stream>>>(qb, Wqb, bq, Qh);
  gemm_bt<0><<<dim3(8, 32), 256, 0, stream>>>(kb, Wkb, bk, Kh);
  // V projection, swapped operands: Wv @ value^T -> Vt [b][h][dk][s]
  gemm_bt<1><<<dim3(32, 8), 256, 0, stream>>>(Wvb, vb, bv, Vt);
  // flash attention: 32 q-tiles x 32 (b,h)
  attn_kernel<<<dim3(32, 32), 256, 0, stream>>>(Qh, Kh, Vt, gprob, maskp, xb);
  // output projection -> f32 d_out
  gemm_bt<2><<<dim3(8, 32), 256, 0, stream>>>(xb, Wob, bo, (float*)d_out);
}

// Round 2
// 353.443 us; speedup vs baseline: 1.0923x; 1.0923x over previous
//
#include <hip/hip_runtime.h>
#include <hip/hip_bf16.h>
#include <stdint.h>

// B=2, S=2048, D=1024, H=16, DK=64
typedef __bf16 bf16x8 __attribute__((ext_vector_type(8)));
typedef float f32x4 __attribute__((ext_vector_type(4)));

__device__ __forceinline__ void gld16(const void* g, void* l) {
  // async global->LDS, 16B/lane. LDS dest must be wave-uniform base + lane*16.
  __builtin_amdgcn_global_load_lds(
      (__attribute__((address_space(1))) void*)(uintptr_t)(g),
      (__attribute__((address_space(3))) void*)(l), 16, 0, 0);
}

// ---------------- cast f32 -> bf16 ----------------
struct CastArgs {
  const float* src[7];
  __bf16* dst[7];
  int n[7];
};

__global__ __launch_bounds__(256) void cast_bf16_kernel(CastArgs a) {
  const int t = blockIdx.y;
  const int i = (blockIdx.x * 256 + threadIdx.x) * 8;
  if (i >= a.n[t]) return;
  const float4* s = (const float4*)(a.src[t] + i);
  float4 v0 = s[0], v1 = s[1];
  bf16x8 o;
  o[0] = (__bf16)v0.x; o[1] = (__bf16)v0.y; o[2] = (__bf16)v0.z; o[3] = (__bf16)v0.w;
  o[4] = (__bf16)v1.x; o[5] = (__bf16)v1.y; o[6] = (__bf16)v1.z; o[7] = (__bf16)v1.w;
  *(bf16x8*)(a.dst[t] + i) = o;
}

// gprob cast (8388608 elements exactly: 4096 blocks x 256 x 8)
__global__ __launch_bounds__(256) void cast_gp_kernel(const float* __restrict__ src,
                                                      __bf16* __restrict__ dst) {
  const int i = (blockIdx.x * 256 + threadIdx.x) * 8;
  const float4* s = (const float4*)(src + i);
  float4 v0 = s[0], v1 = s[1];
  bf16x8 o;
  o[0] = (__bf16)v0.x; o[1] = (__bf16)v0.y; o[2] = (__bf16)v0.z; o[3] = (__bf16)v0.w;
  o[4] = (__bf16)v1.x; o[5] = (__bf16)v1.y; o[6] = (__bf16)v1.z; o[7] = (__bf16)v1.w;
  *(bf16x8*)(dst + i) = o;
}

// ---------------- GEMM: C[m][n] = (sum_k A[m][k]*B[n][k] + bias)*scale, K=1024
// MODE 0: bf16 out -> Qh/Kh layout [b][h][s][dk]  (m=b*2048+s, n=h*64+dk)
// MODE 1: bf16 out -> Vt layout [b][h][dk][s]     (m=h*64+dk [A=W], n=b*2048+s [B=X])
// MODE 2: f32 out  -> [m][n] row-major (final projection)
// LDS chunk-swizzle: 16B chunk c of row r stored at (c ^ (r&3)); source address
// adjusted at staging so global_load_lds (lane-contiguous dest) still works.
template <int MODE>
__global__ __launch_bounds__(256) void gemm_bt(const __bf16* __restrict__ A,
                                               const __bf16* __restrict__ B,
                                               const float* __restrict__ bias,
                                               void* __restrict__ outp, float scale) {
  __shared__ __align__(16) __bf16 As[128 * 32];
  __shared__ __align__(16) __bf16 Bs[128 * 32];
  const int tid = threadIdx.x;
  const int m0 = blockIdx.y * 128;
  const int n0 = blockIdx.x * 128;
  const int lane = tid & 63, wid = tid >> 6;
  const int wm = (wid & 1) * 64, wn = (wid >> 1) * 64;
  const int l16 = lane & 15, quad = lane >> 4;

  const int sc = (tid & 3) ^ ((tid >> 2) & 3);  // swizzled source chunk
  const __bf16* ga = A + (size_t)(m0 + (tid >> 2)) * 1024 + sc * 8;
  const __bf16* gb = B + (size_t)(n0 + (tid >> 2)) * 1024 + sc * 8;
  char* lA = (char*)As + tid * 16;
  char* lB = (char*)Bs + tid * 16;
  // frag read offsets (row stride 64B, swizzled chunk = quad ^ (l16&3))
  const int a_off = (wm + l16) * 64 + ((quad ^ (l16 & 3)) * 16);
  const int b_off = (wn + l16) * 64 + ((quad ^ (l16 & 3)) * 16);

  f32x4 acc[4][4] = {};

  for (int k0 = 0; k0 < 1024; k0 += 32) {
    __syncthreads();
    gld16(ga + k0, lA);
    gld16(ga + k0 + 64 * 1024, lA + 4096);
    gld16(gb + k0, lB);
    gld16(gb + k0 + 64 * 1024, lB + 4096);
    __syncthreads();
    bf16x8 af[4], bfr[4];
#pragma unroll
    for (int mi = 0; mi < 4; ++mi)
      af[mi] = *(const bf16x8*)((const char*)As + a_off + mi * 1024);
#pragma unroll
    for (int ni = 0; ni < 4; ++ni)
      bfr[ni] = *(const bf16x8*)((const char*)Bs + b_off + ni * 1024);
#pragma unroll
    for (int mi = 0; mi < 4; ++mi)
#pragma unroll
      for (int ni = 0; ni < 4; ++ni)
        acc[mi][ni] = __builtin_amdgcn_mfma_f32_16x16x32_bf16(af[mi], bfr[ni],
                                                              acc[mi][ni], 0, 0, 0);
  }

  if (MODE == 2) {
    float* out = (float*)outp;
#pragma unroll
    for (int ni = 0; ni < 4; ++ni) {
      const int col = n0 + wn + ni * 16 + l16;
      const float bb = bias[col];
#pragma unroll
      for (int mi = 0; mi < 4; ++mi)
#pragma unroll
        for (int r = 0; r < 4; ++r) {
          const int row = m0 + wm + mi * 16 + quad * 4 + r;
          out[(size_t)row * 1024 + col] = (acc[mi][ni][r] + bb) * scale;
        }
    }
  } else if (MODE == 0) {
    __bf16* out = (__bf16*)outp;
#pragma unroll
    for (int ni = 0; ni < 4; ++ni) {
      const int col = n0 + wn + ni * 16 + l16;
      const int h = col >> 6, dk = col & 63;
      const float bb = bias[col];
#pragma unroll
      for (int mi = 0; mi < 4; ++mi)
#pragma unroll
        for (int r = 0; r < 4; ++r) {
          const int row = m0 + wm + mi * 16 + quad * 4 + r;
          const int b = row >> 11, s = row & 2047;
          out[((size_t)(b * 16 + h) * 2048 + s) * 64 + dk] =
              (__bf16)((acc[mi][ni][r] + bb) * scale);
        }
    }
  } else {  // MODE 1: A=W (m=feature), B=X (n=token); store Vt[b][h][dk][s]
    __bf16* out = (__bf16*)outp;
#pragma unroll
    for (int mi = 0; mi < 4; ++mi)
#pragma unroll
      for (int r = 0; r < 4; ++r) {
        const int rowm = m0 + wm + mi * 16 + quad * 4 + r;
        const int h = rowm >> 6, dk = rowm & 63;
        const float bb = bias[rowm];
#pragma unroll
        for (int ni = 0; ni < 4; ++ni) {
          const int coln = n0 + wn + ni * 16 + l16;
          const int b = coln >> 11, s = coln & 2047;
          out[((size_t)(b * 16 + h) * 64 + dk) * 2048 + s] =
              (__bf16)((acc[mi][ni][r] + bb) * scale);
        }
      }
  }
}

// ---------------- flash attention, max-free softmax, post-softmax g-scale ---
// Qh,Kh: [b][h][s][64] bf16 (Q pre-scaled by 1/8); Vt: [b][h][64][2048] bf16;
// gp16: [b][s][s] bf16; out xb: [b][s][1024] bf16
// LDS tiles use 16B-chunk swizzle c' = c ^ (row&7) to kill b128 bank conflicts.
__global__ __launch_bounds__(256) void attn_kernel(
    const __bf16* __restrict__ Qh, const __bf16* __restrict__ Kh,
    const __bf16* __restrict__ Vt, const __bf16* __restrict__ gp16,
    const int* __restrict__ maskp, __bf16* __restrict__ xb) {
  __shared__ __align__(16) __bf16 Qs[64 * 64];
  __shared__ __align__(16) __bf16 Ks[64 * 64];
  __shared__ __align__(16) __bf16 Vs[64 * 64];   // Vt tile: [dk][s_rel]
  __shared__ __align__(16) __bf16 Ps[4][16 * 64];

  const int tid = threadIdx.x;
  const int qt = blockIdx.x, bh = blockIdx.y;
  const int b = bh >> 4, h = bh & 15;
  const int q0 = qt * 64;
  const int lane = tid & 63, wid = tid >> 6, l16 = lane & 15, quad = lane >> 4;
  const size_t head_off = (size_t)bh * (2048 * 64);

  const int srow = tid >> 3;                 // staging row 0..31
  const int sc8 = (tid & 7) ^ (srow & 7);    // swizzled source chunk
  const int fxor = (l16 & 7);                // frag-read chunk xor

  {
    const __bf16* gq = Qh + head_off + (size_t)(q0 + srow) * 64 + sc8 * 8;
    gld16(gq, (char*)Qs + tid * 16);
    gld16(gq + 32 * 64, (char*)Qs + 4096 + tid * 16);
  }
  __syncthreads();
  bf16x8 aq[2];
  aq[0] = *(const bf16x8*)((const char*)Qs + (wid * 16 + l16) * 128 +
                           ((quad ^ fxor) * 16));
  aq[1] = *(const bf16x8*)((const char*)Qs + (wid * 16 + l16) * 128 +
                           (((4 + quad) ^ fxor) * 16));

  f32x4 o[4] = {};
  float lp[4] = {0.f, 0.f, 0.f, 0.f};
  int irow[4];
#pragma unroll
  for (int r = 0; r < 4; ++r) irow[r] = q0 + wid * 16 + quad * 4 + r;

  const __bf16* gk0 = Kh + head_off + (size_t)srow * 64 + sc8 * 8;
  const __bf16* gv0 = Vt + head_off + (size_t)srow * 2048 + sc8 * 8;
  const int* mrow = maskp + b * 2048;
  const __bf16* gpb = gp16 + (size_t)b * 2048 * 2048;

  for (int kt = 0; kt < 32; ++kt) {
    __syncthreads();  // protect Ks/Vs from previous iteration's readers
    gld16(gk0 + kt * 4096, (char*)Ks + tid * 16);
    gld16(gk0 + kt * 4096 + 2048, (char*)Ks + 4096 + tid * 16);
    gld16(gv0 + kt * 64, (char*)Vs + tid * 16);
    gld16(gv0 + kt * 64 + 32 * 2048, (char*)Vs + 4096 + tid * 16);

    // issue mask + gprob loads early (overlap with staging + MFMA)
    const int jbase = kt * 64;
    int mj[4];
#pragma unroll
    for (int ni = 0; ni < 4; ++ni) mj[ni] = mrow[jbase + ni * 16 + l16];
    float gf[4][4];
#pragma unroll
    for (int r = 0; r < 4; ++r) {
      const __bf16* gpr = gpb + (size_t)irow[r] * 2048 + jbase + l16;
#pragma unroll
      for (int ni = 0; ni < 4; ++ni) gf[ni][r] = (float)gpr[ni * 16];
    }
    __syncthreads();  // includes vmcnt(0): staging landed

    // QK^T: D[m=q_rel][n=k_rel]  (Q pre-scaled by 1/8)
    f32x4 sc[4] = {};
#pragma unroll
    for (int kh = 0; kh < 2; ++kh)
#pragma unroll
      for (int ni = 0; ni < 4; ++ni) {
        bf16x8 bk = *(const bf16x8*)((const char*)Ks + (ni * 16 + l16) * 128 +
                                     (((kh * 4 + quad) ^ fxor) * 16));
        sc[ni] = __builtin_amdgcn_mfma_f32_16x16x32_bf16(aq[kh], bk, sc[ni], 0, 0, 0);
      }

    // max-free softmax: p = exp(s) (scores bounded ~|3|), masked -> 0.
    // l accumulates per-lane; cross-lane reduce deferred to epilogue.
    float pv[4][4];
    if (kt != qt) {  // common path: no diagonal in this tile
#pragma unroll
      for (int ni = 0; ni < 4; ++ni)
#pragma unroll
        for (int r = 0; r < 4; ++r) {
          const float e = __expf(sc[ni][r]);
          const float p = (mj[ni] != 0) ? e : 0.f;
          lp[r] += p;
          pv[ni][r] = p * gf[ni][r];
        }
    } else {  // diagonal tile: j==irow[r] <=> ni==wid && l16==quad*4+r
#pragma unroll
      for (int ni = 0; ni < 4; ++ni)
#pragma unroll
        for (int r = 0; r < 4; ++r) {
          const float e = __expf(sc[ni][r]);
          const bool diag = (ni == wid) && (l16 == quad * 4 + r);
          const float p = (mj[ni] != 0 || diag) ? e : 0.f;
          lp[r] += p;
          pv[ni][r] = p * gf[ni][r];
        }
    }

    // P' -> per-wave LDS tile (C-layout -> A-layout), swizzled chunks
#pragma unroll
    for (int ni = 0; ni < 4; ++ni)
#pragma unroll
      for (int r = 0; r < 4; ++r) {
        const int prow = quad * 4 + r;
        const int pchunk = (ni * 2 + (l16 >> 3)) ^ (prow & 7);
        *(__bf16*)((char*)&Ps[wid][0] + prow * 128 + pchunk * 16 + (l16 & 7) * 2) =
            (__bf16)pv[ni][r];
      }
    asm volatile("s_waitcnt lgkmcnt(0)" ::: "memory");  // wave-private write->read

    // O += P' @ V
#pragma unroll
    for (int kh = 0; kh < 2; ++kh) {
      bf16x8 ap = *(const bf16x8*)((const char*)&Ps[wid][0] + l16 * 128 +
                                   (((kh * 4 + quad) ^ fxor) * 16));
#pragma unroll
      for (int ni = 0; ni < 4; ++ni) {
        bf16x8 bv = *(const bf16x8*)((const char*)Vs + (ni * 16 + l16) * 128 +
                                     (((kh * 4 + quad) ^ fxor) * 16));
        o[ni] = __builtin_amdgcn_mfma_f32_16x16x32_bf16(ap, bv, o[ni], 0, 0, 0);
      }
    }
  }

  // reduce l across the 16 lanes holding each row, then write x = O / l
#pragma unroll
  for (int r = 0; r < 4; ++r) {
    lp[r] += __shfl_xor(lp[r], 1);
    lp[r] += __shfl_xor(lp[r], 2);
    lp[r] += __shfl_xor(lp[r], 4);
    lp[r] += __shfl_xor(lp[r], 8);
    lp[r] = 1.f / lp[r];
  }
#pragma unroll
  for (int ni = 0; ni < 4; ++ni) {
    const int dk = ni * 16 + l16;
#pragma unroll
    for (int r = 0; r < 4; ++r) {
      const float val = o[ni][r] * lp[r];
      xb[((size_t)(b * 2048 + irow[r])) * 1024 + h * 64 + dk] = (__bf16)val;
    }
  }
}

extern "C" void kernel_launch(void* const* d_in, const int* in_sizes, int n_in,
                              void* d_out, int out_size, void* d_ws, size_t ws_size,
                              hipStream_t stream) {
  const float* query = (const float*)d_in[0];
  const float* key_  = (const float*)d_in[1];
  const float* value = (const float*)d_in[2];
  const float* gprob = (const float*)d_in[3];
  const int*   maskp = (const int*)d_in[4];
  const float* Wq = (const float*)d_in[5];
  const float* bq = (const float*)d_in[6];
  const float* Wk = (const float*)d_in[7];
  const float* bk = (const float*)d_in[8];
  const float* Wv = (const float*)d_in[9];
  const float* bv = (const float*)d_in[10];
  const float* Wo = (const float*)d_in[11];
  const float* bo = (const float*)d_in[12];

  char* ws = (char*)d_ws;
  const size_t MB = 1 << 20;
  __bf16* qb  = (__bf16*)(ws + 0 * MB);   // dead after gemm Q
  __bf16* kb  = (__bf16*)(ws + 8 * MB);   // dead after gemm K
  __bf16* vb  = (__bf16*)(ws + 16 * MB);  // dead after gemm V
  __bf16* Wqb = (__bf16*)(ws + 24 * MB);
  __bf16* Wkb = (__bf16*)(ws + 26 * MB);
  __bf16* Wvb = (__bf16*)(ws + 28 * MB);
  __bf16* Wob = (__bf16*)(ws + 30 * MB);
  __bf16* Qh  = (__bf16*)(ws + 32 * MB);
  __bf16* Kh  = (__bf16*)(ws + 40 * MB);
  __bf16* Vt  = (__bf16*)(ws + 48 * MB);
  __bf16* xb  = (__bf16*)(ws + 56 * MB);
  __bf16* gp16 = (__bf16*)(ws + 0 * MB);  // overlays qb+kb after projections

  CastArgs ca;
  ca.src[0] = query; ca.dst[0] = qb;  ca.n[0] = 4194304;
  ca.src[1] = key_;  ca.dst[1] = kb;  ca.n[1] = 4194304;
  ca.src[2] = value; ca.dst[2] = vb;  ca.n[2] = 4194304;
  ca.src[3] = Wq;    ca.dst[3] = Wqb; ca.n[3] = 1048576;
  ca.src[4] = Wk;    ca.dst[4] = Wkb; ca.n[4] = 1048576;
  ca.src[5] = Wv;    ca.dst[5] = Wvb; ca.n[5] = 1048576;
  ca.src[6] = Wo;    ca.dst[6] = Wob; ca.n[6] = 1048576;

  cast_bf16_kernel<<<dim3(2048, 7), 256, 0, stream>>>(ca);
  // Q projection pre-scaled by 1/sqrt(DK)=0.125; K,V unscaled
  gemm_bt<0><<<dim3(8, 32), 256, 0, stream>>>(qb, Wqb, bq, Qh, 0.125f);
  gemm_bt<0><<<dim3(8, 32), 256, 0, stream>>>(kb, Wkb, bk, Kh, 1.0f);
  gemm_bt<1><<<dim3(32, 8), 256, 0, stream>>>(Wvb, vb, bv, Vt, 1.0f);
  // cast gprob AFTER projections (gp16 overlays dead qb/kb: stays within 64MB ws)
  cast_gp_kernel<<<dim3(4096), 256, 0, stream>>>(gprob, gp16);
  attn_kernel<<<dim3(32, 32), 256, 0, stream>>>(Qh, Kh, Vt, gp16, maskp, xb);
  gemm_bt<2><<<dim3(8, 32), 256, 0, stream>>>(xb, Wob, bo, (float*)d_out, 1.0f);
}

// Round 3
// 333.525 us; speedup vs baseline: 1.1576x; 1.0597x over previous
//
#include <hip/hip_runtime.h>
#include <hip/hip_bf16.h>
#include <stdint.h>

// B=2, S=2048, D=1024, H=16, DK=64
typedef __bf16 bf16x8 __attribute__((ext_vector_type(8)));
typedef float f32x4 __attribute__((ext_vector_type(4)));

__device__ __forceinline__ void gld16(const void* g, void* l) {
  // async global->LDS, 16B/lane. LDS dest must be wave-uniform base + lane*16.
  __builtin_amdgcn_global_load_lds(
      (__attribute__((address_space(1))) void*)(uintptr_t)(g),
      (__attribute__((address_space(3))) void*)(l), 16, 0, 0);
}

// ---------------- cast f32 -> bf16 ----------------
struct CastArgs {
  const float* src[7];
  __bf16* dst[7];
  int n[7];
};

__global__ __launch_bounds__(256) void cast_bf16_kernel(CastArgs a) {
  const int t = blockIdx.y;
  const int i = (blockIdx.x * 256 + threadIdx.x) * 8;
  if (i >= a.n[t]) return;
  const float4* s = (const float4*)(a.src[t] + i);
  float4 v0 = s[0], v1 = s[1];
  bf16x8 o;
  o[0] = (__bf16)v0.x; o[1] = (__bf16)v0.y; o[2] = (__bf16)v0.z; o[3] = (__bf16)v0.w;
  o[4] = (__bf16)v1.x; o[5] = (__bf16)v1.y; o[6] = (__bf16)v1.z; o[7] = (__bf16)v1.w;
  *(bf16x8*)(a.dst[t] + i) = o;
}

// gprob cast (8388608 elements exactly: 4096 blocks x 256 x 8)
__global__ __launch_bounds__(256) void cast_gp_kernel(const float* __restrict__ src,
                                                      __bf16* __restrict__ dst) {
  const int i = (blockIdx.x * 256 + threadIdx.x) * 8;
  const float4* s = (const float4*)(src + i);
  float4 v0 = s[0], v1 = s[1];
  bf16x8 o;
  o[0] = (__bf16)v0.x; o[1] = (__bf16)v0.y; o[2] = (__bf16)v0.z; o[3] = (__bf16)v0.w;
  o[4] = (__bf16)v1.x; o[5] = (__bf16)v1.y; o[6] = (__bf16)v1.z; o[7] = (__bf16)v1.w;
  *(bf16x8*)(dst + i) = o;
}

// ---------------- fused Q/K/V projection GEMM ----------------
// z=0: Q = xq @ Wq^T (scale 1/8) -> [b][h][s][dk]
// z=1: K = xk @ Wk^T             -> [b][h][s][dk]
// z=2: V^T = Wv @ xv^T           -> [b][h][dk][s]
// 768 blocks total (3 blocks/CU) so barrier drains overlap across blocks.
struct QkvArgs {
  const __bf16* A[3];
  const __bf16* B[3];
  const float* bias[3];
  __bf16* out[3];
};

__global__ __launch_bounds__(256) void qkv_gemm(QkvArgs args) {
  __shared__ __align__(16) __bf16 As[128 * 32];
  __shared__ __align__(16) __bf16 Bs[128 * 32];
  const int tid = threadIdx.x;
  const int z = blockIdx.y;
  const int bx = blockIdx.x;
  const int m0 = (z < 2 ? (bx >> 3) : (bx & 7)) * 128;
  const int n0 = (z < 2 ? (bx & 7) : (bx >> 3)) * 128;
  const __bf16* A = args.A[z];
  const __bf16* B = args.B[z];
  const float* bias = args.bias[z];
  __bf16* out = args.out[z];
  const float scale = (z == 0) ? 0.125f : 1.0f;

  const int lane = tid & 63, wid = tid >> 6;
  const int wm = (wid & 1) * 64, wn = (wid >> 1) * 64;
  const int l16 = lane & 15, quad = lane >> 4;

  const int sc = (tid & 3) ^ ((tid >> 2) & 3);  // swizzled source chunk
  const __bf16* ga = A + (size_t)(m0 + (tid >> 2)) * 1024 + sc * 8;
  const __bf16* gb = B + (size_t)(n0 + (tid >> 2)) * 1024 + sc * 8;
  char* lA = (char*)As + tid * 16;
  char* lB = (char*)Bs + tid * 16;
  const int a_off = (wm + l16) * 64 + ((quad ^ (l16 & 3)) * 16);
  const int b_off = (wn + l16) * 64 + ((quad ^ (l16 & 3)) * 16);

  f32x4 acc[4][4] = {};

  for (int k0 = 0; k0 < 1024; k0 += 32) {
    __syncthreads();
    gld16(ga + k0, lA);
    gld16(ga + k0 + 64 * 1024, lA + 4096);
    gld16(gb + k0, lB);
    gld16(gb + k0 + 64 * 1024, lB + 4096);
    __syncthreads();
    bf16x8 af[4], bfr[4];
#pragma unroll
    for (int mi = 0; mi < 4; ++mi)
      af[mi] = *(const bf16x8*)((const char*)As + a_off + mi * 1024);
#pragma unroll
    for (int ni = 0; ni < 4; ++ni)
      bfr[ni] = *(const bf16x8*)((const char*)Bs + b_off + ni * 1024);
#pragma unroll
    for (int mi = 0; mi < 4; ++mi)
#pragma unroll
      for (int ni = 0; ni < 4; ++ni)
        acc[mi][ni] = __builtin_amdgcn_mfma_f32_16x16x32_bf16(af[mi], bfr[ni],
                                                              acc[mi][ni], 0, 0, 0);
  }

  if (z < 2) {  // token-major -> [b][h][s][dk]
#pragma unroll
    for (int ni = 0; ni < 4; ++ni) {
      const int col = n0 + wn + ni * 16 + l16;
      const int h = col >> 6, dk = col & 63;
      const float bb = bias[col];
#pragma unroll
      for (int mi = 0; mi < 4; ++mi)
#pragma unroll
        for (int r = 0; r < 4; ++r) {
          const int row = m0 + wm + mi * 16 + quad * 4 + r;
          const int b = row >> 11, s = row & 2047;
          out[((size_t)(b * 16 + h) * 2048 + s) * 64 + dk] =
              (__bf16)((acc[mi][ni][r] + bb) * scale);
        }
    }
  } else {  // V: A=W (m=feature), B=X (n=token); store Vt[b][h][dk][s]
#pragma unroll
    for (int mi = 0; mi < 4; ++mi)
#pragma unroll
      for (int r = 0; r < 4; ++r) {
        const int rowm = m0 + wm + mi * 16 + quad * 4 + r;
        const int h = rowm >> 6, dk = rowm & 63;
        const float bb = bias[rowm];
#pragma unroll
        for (int ni = 0; ni < 4; ++ni) {
          const int coln = n0 + wn + ni * 16 + l16;
          const int b = coln >> 11, s = coln & 2047;
          out[((size_t)(b * 16 + h) * 64 + dk) * 2048 + s] =
              (__bf16)(acc[mi][ni][r] + bb);
        }
      }
  }
}

// ---------------- output projection GEMM (f32 out) ----------------
__global__ __launch_bounds__(256) void gemm_out(const __bf16* __restrict__ A,
                                                const __bf16* __restrict__ B,
                                                const float* __restrict__ bias,
                                                float* __restrict__ out) {
  __shared__ __align__(16) __bf16 As[128 * 32];
  __shared__ __align__(16) __bf16 Bs[128 * 32];
  const int tid = threadIdx.x;
  const int m0 = blockIdx.y * 128;
  const int n0 = blockIdx.x * 128;
  const int lane = tid & 63, wid = tid >> 6;
  const int wm = (wid & 1) * 64, wn = (wid >> 1) * 64;
  const int l16 = lane & 15, quad = lane >> 4;

  const int sc = (tid & 3) ^ ((tid >> 2) & 3);
  const __bf16* ga = A + (size_t)(m0 + (tid >> 2)) * 1024 + sc * 8;
  const __bf16* gb = B + (size_t)(n0 + (tid >> 2)) * 1024 + sc * 8;
  char* lA = (char*)As + tid * 16;
  char* lB = (char*)Bs + tid * 16;
  const int a_off = (wm + l16) * 64 + ((quad ^ (l16 & 3)) * 16);
  const int b_off = (wn + l16) * 64 + ((quad ^ (l16 & 3)) * 16);

  f32x4 acc[4][4] = {};

  for (int k0 = 0; k0 < 1024; k0 += 32) {
    __syncthreads();
    gld16(ga + k0, lA);
    gld16(ga + k0 + 64 * 1024, lA + 4096);
    gld16(gb + k0, lB);
    gld16(gb + k0 + 64 * 1024, lB + 4096);
    __syncthreads();
    bf16x8 af[4], bfr[4];
#pragma unroll
    for (int mi = 0; mi < 4; ++mi)
      af[mi] = *(const bf16x8*)((const char*)As + a_off + mi * 1024);
#pragma unroll
    for (int ni = 0; ni < 4; ++ni)
      bfr[ni] = *(const bf16x8*)((const char*)Bs + b_off + ni * 1024);
#pragma unroll
    for (int mi = 0; mi < 4; ++mi)
#pragma unroll
      for (int ni = 0; ni < 4; ++ni)
        acc[mi][ni] = __builtin_amdgcn_mfma_f32_16x16x32_bf16(af[mi], bfr[ni],
                                                              acc[mi][ni], 0, 0, 0);
  }

#pragma unroll
  for (int ni = 0; ni < 4; ++ni) {
    const int col = n0 + wn + ni * 16 + l16;
    const float bb = bias[col];
#pragma unroll
    for (int mi = 0; mi < 4; ++mi)
#pragma unroll
      for (int r = 0; r < 4; ++r) {
        const int row = m0 + wm + mi * 16 + quad * 4 + r;
        out[(size_t)row * 1024 + col] = acc[mi][ni][r] + bb;
      }
  }
}

// ---------------- flash attention, max-free softmax, post-softmax g-scale ---
// Qh,Kh: [b][h][s][64] bf16 (Q pre-scaled by 1/8); Vt: [b][h][64][2048] bf16;
// gp16: [b][s][s] bf16; out xb: [b][s][1024] bf16
// g is applied in A-frag layout (2 coalesced 16B loads/kt) after the P LDS
// round-trip; mask comes from a one-time per-block ballot bitmask in LDS.
__global__ __launch_bounds__(256) void attn_kernel(
    const __bf16* __restrict__ Qh, const __bf16* __restrict__ Kh,
    const __bf16* __restrict__ Vt, const __bf16* __restrict__ gp16,
    const int* __restrict__ maskp, __bf16* __restrict__ xb) {
  __shared__ __align__(16) __bf16 Qs[64 * 64];
  __shared__ __align__(16) __bf16 Ks[64 * 64];
  __shared__ __align__(16) __bf16 Vs[64 * 64];   // Vt tile: [dk][s_rel]
  __shared__ __align__(16) __bf16 Ps[4][16 * 64];
  __shared__ unsigned long long mbits[32];

  const int tid = threadIdx.x;
  const int qt = blockIdx.x, bh = blockIdx.y;
  const int b = bh >> 4, h = bh & 15;
  const int q0 = qt * 64;
  const int lane = tid & 63, wid = tid >> 6, l16 = lane & 15, quad = lane >> 4;
  const size_t head_off = (size_t)bh * (2048 * 64);

  const int srow = tid >> 3;                 // staging row 0..31
  const int sc8 = (tid & 7) ^ (srow & 7);    // swizzled source chunk
  const int fxor = (l16 & 7);                // frag-read chunk xor

  {
    const __bf16* gq = Qh + head_off + (size_t)(q0 + srow) * 64 + sc8 * 8;
    gld16(gq, (char*)Qs + tid * 16);
    gld16(gq + 32 * 64, (char*)Qs + 4096 + tid * 16);
  }
  // one-time mask ballot: mbits[kt] bit j = mask[b][kt*64+j]
  {
    const int* mr = maskp + b * 2048;
#pragma unroll
    for (int t = 0; t < 8; ++t) {
      const int kt2 = wid * 8 + t;
      const int mv = mr[kt2 * 64 + lane];
      const unsigned long long bal = __ballot(mv != 0);
      if (lane == 0) mbits[kt2] = bal;
    }
  }
  __syncthreads();
  bf16x8 aq[2];
  aq[0] = *(const bf16x8*)((const char*)Qs + (wid * 16 + l16) * 128 +
                           ((quad ^ fxor) * 16));
  aq[1] = *(const bf16x8*)((const char*)Qs + (wid * 16 + l16) * 128 +
                           (((4 + quad) ^ fxor) * 16));

  f32x4 o[4] = {};
  float lp[4] = {0.f, 0.f, 0.f, 0.f};
  int irow[4];
#pragma unroll
  for (int r = 0; r < 4; ++r) irow[r] = q0 + wid * 16 + quad * 4 + r;

  const __bf16* gk0 = Kh + head_off + (size_t)srow * 64 + sc8 * 8;
  const __bf16* gv0 = Vt + head_off + (size_t)srow * 2048 + sc8 * 8;
  // g in A-frag layout: row q0+wid*16+l16, col chunk (kh*4+quad)*8
  const __bf16* gpl = gp16 + (size_t)b * 2048 * 2048 +
                      (size_t)(q0 + wid * 16 + l16) * 2048 + quad * 8;

  for (int kt = 0; kt < 32; ++kt) {
    __syncthreads();  // protect Ks/Vs from previous iteration's readers
    gld16(gk0 + kt * 4096, (char*)Ks + tid * 16);
    gld16(gk0 + kt * 4096 + 2048, (char*)Ks + 4096 + tid * 16);
    gld16(gv0 + kt * 64, (char*)Vs + tid * 16);
    gld16(gv0 + kt * 64 + 32 * 2048, (char*)Vs + 4096 + tid * 16);

    // g fragment loads (A-layout, coalesced 16B) — drained by the barrier below
    bf16x8 g8_0 = *(const bf16x8*)(gpl + kt * 64);
    bf16x8 g8_1 = *(const bf16x8*)(gpl + kt * 64 + 32);

    // mask bits for this k-tile (broadcast LDS read + bit tests)
    const unsigned long long sh = mbits[kt] >> l16;
    const uint32_t shlo = (uint32_t)sh, shhi = (uint32_t)(sh >> 32);
    const bool mk[4] = {(shlo & 1) != 0, (shlo & 0x10000u) != 0,
                        (shhi & 1) != 0, (shhi & 0x10000u) != 0};
    __syncthreads();  // includes vmcnt(0): staging landed

    // QK^T: D[m=q_rel][n=k_rel]  (Q pre-scaled by 1/8)
    f32x4 sc[4] = {};
#pragma unroll
    for (int kh = 0; kh < 2; ++kh)
#pragma unroll
      for (int ni = 0; ni < 4; ++ni) {
        bf16x8 bk = *(const bf16x8*)((const char*)Ks + (ni * 16 + l16) * 128 +
                                     (((kh * 4 + quad) ^ fxor) * 16));
        sc[ni] = __builtin_amdgcn_mfma_f32_16x16x32_bf16(aq[kh], bk, sc[ni], 0, 0, 0);
      }

    // max-free softmax: p = exp(s) (scores bounded ~|3|), masked -> 0.
    float pw[4][4];
    if (kt != qt) {
#pragma unroll
      for (int ni = 0; ni < 4; ++ni)
#pragma unroll
        for (int r = 0; r < 4; ++r) {
          const float e = __expf(sc[ni][r]);
          const float p = mk[ni] ? e : 0.f;
          lp[r] += p;
          pw[ni][r] = p;
        }
    } else {  // diagonal tile: j==irow[r] <=> ni==wid && l16==quad*4+r
#pragma unroll
      for (int ni = 0; ni < 4; ++ni)
#pragma unroll
        for (int r = 0; r < 4; ++r) {
          const float e = __expf(sc[ni][r]);
          const bool diag = (ni == wid) && (l16 == quad * 4 + r);
          const float p = (mk[ni] || diag) ? e : 0.f;
          lp[r] += p;
          pw[ni][r] = p;
        }
    }

    // P (masked, un-g-scaled) -> per-wave LDS tile (C-layout -> A-layout)
#pragma unroll
    for (int ni = 0; ni < 4; ++ni)
#pragma unroll
      for (int r = 0; r < 4; ++r) {
        const int prow = quad * 4 + r;
        const int pchunk = (ni * 2 + (l16 >> 3)) ^ (prow & 7);
        *(__bf16*)((char*)&Ps[wid][0] + prow * 128 + pchunk * 16 + (l16 & 7) * 2) =
            (__bf16)pw[ni][r];
      }
    asm volatile("s_waitcnt lgkmcnt(0)" ::: "memory");  // wave-private write->read

    // O += (P .* g) @ V — g applied on the A-fragment (contiguous per lane)
#pragma unroll
    for (int kh = 0; kh < 2; ++kh) {
      bf16x8 ap = *(const bf16x8*)((const char*)&Ps[wid][0] + l16 * 128 +
                                   (((kh * 4 + quad) ^ fxor) * 16));
      const bf16x8 g8 = kh ? g8_1 : g8_0;
      bf16x8 apg;
#pragma unroll
      for (int j = 0; j < 8; ++j)
        apg[j] = (__bf16)((float)ap[j] * (float)g8[j]);
#pragma unroll
      for (int ni = 0; ni < 4; ++ni) {
        bf16x8 bv = *(const bf16x8*)((const char*)Vs + (ni * 16 + l16) * 128 +
                                     (((kh * 4 + quad) ^ fxor) * 16));
        o[ni] = __builtin_amdgcn_mfma_f32_16x16x32_bf16(apg, bv, o[ni], 0, 0, 0);
      }
    }
  }

  // reduce l across the 16 lanes holding each row, then write x = O / l
#pragma unroll
  for (int r = 0; r < 4; ++r) {
    lp[r] += __shfl_xor(lp[r], 1);
    lp[r] += __shfl_xor(lp[r], 2);
    lp[r] += __shfl_xor(lp[r], 4);
    lp[r] += __shfl_xor(lp[r], 8);
    lp[r] = 1.f / lp[r];
  }
#pragma unroll
  for (int ni = 0; ni < 4; ++ni) {
    const int dk = ni * 16 + l16;
#pragma unroll
    for (int r = 0; r < 4; ++r) {
      const float val = o[ni][r] * lp[r];
      xb[((size_t)(b * 2048 + irow[r])) * 1024 + h * 64 + dk] = (__bf16)val;
    }
  }
}

extern "C" void kernel_launch(void* const* d_in, const int* in_sizes, int n_in,
                              void* d_out, int out_size, void* d_ws, size_t ws_size,
                              hipStream_t stream) {
  const float* query = (const float*)d_in[0];
  const float* key_  = (const float*)d_in[1];
  const float* value = (const float*)d_in[2];
  const float* gprob = (const float*)d_in[3];
  const int*   maskp = (const int*)d_in[4];
  const float* Wq = (const float*)d_in[5];
  const float* bq = (const float*)d_in[6];
  const float* Wk = (const float*)d_in[7];
  const float* bk = (const float*)d_in[8];
  const float* Wv = (const float*)d_in[9];
  const float* bv = (const float*)d_in[10];
  const float* Wo = (const float*)d_in[11];
  const float* bo = (const float*)d_in[12];

  char* ws = (char*)d_ws;
  const size_t MB = 1 << 20;
  __bf16* qb  = (__bf16*)(ws + 0 * MB);   // dead after QKV gemm
  __bf16* kb  = (__bf16*)(ws + 8 * MB);   // dead after QKV gemm
  __bf16* vb  = (__bf16*)(ws + 16 * MB);  // dead after QKV gemm
  __bf16* Wqb = (__bf16*)(ws + 24 * MB);
  __bf16* Wkb = (__bf16*)(ws + 26 * MB);
  __bf16* Wvb = (__bf16*)(ws + 28 * MB);
  __bf16* Wob = (__bf16*)(ws + 30 * MB);
  __bf16* Qh  = (__bf16*)(ws + 32 * MB);
  __bf16* Kh  = (__bf16*)(ws + 40 * MB);
  __bf16* Vt  = (__bf16*)(ws + 48 * MB);
  __bf16* xb  = (__bf16*)(ws + 56 * MB);
  __bf16* gp16 = (__bf16*)(ws + 0 * MB);  // overlays qb+kb after projections

  CastArgs ca;
  ca.src[0] = query; ca.dst[0] = qb;  ca.n[0] = 4194304;
  ca.src[1] = key_;  ca.dst[1] = kb;  ca.n[1] = 4194304;
  ca.src[2] = value; ca.dst[2] = vb;  ca.n[2] = 4194304;
  ca.src[3] = Wq;    ca.dst[3] = Wqb; ca.n[3] = 1048576;
  ca.src[4] = Wk;    ca.dst[4] = Wkb; ca.n[4] = 1048576;
  ca.src[5] = Wv;    ca.dst[5] = Wvb; ca.n[5] = 1048576;
  ca.src[6] = Wo;    ca.dst[6] = Wob; ca.n[6] = 1048576;
  cast_bf16_kernel<<<dim3(2048, 7), 256, 0, stream>>>(ca);

  QkvArgs qa;
  qa.A[0] = qb;  qa.B[0] = Wqb; qa.bias[0] = bq; qa.out[0] = Qh;
  qa.A[1] = kb;  qa.B[1] = Wkb; qa.bias[1] = bk; qa.out[1] = Kh;
  qa.A[2] = Wvb; qa.B[2] = vb;  qa.bias[2] = bv; qa.out[2] = Vt;
  qkv_gemm<<<dim3(256, 3), 256, 0, stream>>>(qa);

  // cast gprob AFTER projections (gp16 overlays dead qb/kb)
  cast_gp_kernel<<<dim3(4096), 256, 0, stream>>>(gprob, gp16);
  attn_kernel<<<dim3(32, 32), 256, 0, stream>>>(Qh, Kh, Vt, gp16, maskp, xb);
  gemm_out<<<dim3(8, 32), 256, 0, stream>>>(xb, Wob, bo, (float*)d_out);
}

// Round 4
// 323.804 us; speedup vs baseline: 1.1923x; 1.0300x over previous
//
#include <hip/hip_runtime.h>
#include <hip/hip_bf16.h>
#include <stdint.h>

// B=2, S=2048, D=1024, H=16, DK=64
typedef __bf16 bf16x8 __attribute__((ext_vector_type(8)));
typedef float f32x4 __attribute__((ext_vector_type(4)));

#define QSCALE 0.1803368801111244f  // (1/8) * log2(e): softmax via exp2

__device__ __forceinline__ void gld16(const void* g, void* l) {
  // async global->LDS, 16B/lane. LDS dest must be wave-uniform base + lane*16.
  __builtin_amdgcn_global_load_lds(
      (__attribute__((address_space(1))) void*)(uintptr_t)(g),
      (__attribute__((address_space(3))) void*)(l), 16, 0, 0);
}

// ---------------- cast f32 -> bf16 (7 tensors, one launch) ----------------
struct CastArgs {
  const float* src[7];
  __bf16* dst[7];
  int n[7];
};

__global__ __launch_bounds__(256) void cast_bf16_kernel(CastArgs a) {
  const int t = blockIdx.y;
  const int i = (blockIdx.x * 256 + threadIdx.x) * 8;
  if (i >= a.n[t]) return;
  const float4* s = (const float4*)(a.src[t] + i);
  float4 v0 = s[0], v1 = s[1];
  bf16x8 o;
  o[0] = (__bf16)v0.x; o[1] = (__bf16)v0.y; o[2] = (__bf16)v0.z; o[3] = (__bf16)v0.w;
  o[4] = (__bf16)v1.x; o[5] = (__bf16)v1.y; o[6] = (__bf16)v1.z; o[7] = (__bf16)v1.w;
  *(bf16x8*)(a.dst[t] + i) = o;
}

// ---------------- fused Q/K/V projection GEMM ----------------
// z=0: Q = xq @ Wq^T (scale QSCALE) -> [b][h][s][dk]
// z=1: K = xk @ Wk^T               -> [b][h][s][dk]
// z=2: V^T = Wv @ xv^T             -> [b][h][dk][s]
struct QkvArgs {
  const __bf16* A[3];
  const __bf16* B[3];
  const float* bias[3];
  __bf16* out[3];
};

__global__ __launch_bounds__(256) void qkv_gemm(QkvArgs args) {
  __shared__ __align__(16) __bf16 As[128 * 32];
  __shared__ __align__(16) __bf16 Bs[128 * 32];
  const int tid = threadIdx.x;
  const int z = blockIdx.y;
  const int bx = blockIdx.x;
  const int m0 = (z < 2 ? (bx >> 3) : (bx & 7)) * 128;
  const int n0 = (z < 2 ? (bx & 7) : (bx >> 3)) * 128;
  const __bf16* A = args.A[z];
  const __bf16* B = args.B[z];
  const float* bias = args.bias[z];
  __bf16* out = args.out[z];
  const float scale = (z == 0) ? QSCALE : 1.0f;

  const int lane = tid & 63, wid = tid >> 6;
  const int wm = (wid & 1) * 64, wn = (wid >> 1) * 64;
  const int l16 = lane & 15, quad = lane >> 4;

  const int sc = (tid & 3) ^ ((tid >> 2) & 3);  // swizzled source chunk
  const __bf16* ga = A + (size_t)(m0 + (tid >> 2)) * 1024 + sc * 8;
  const __bf16* gb = B + (size_t)(n0 + (tid >> 2)) * 1024 + sc * 8;
  char* lA = (char*)As + tid * 16;
  char* lB = (char*)Bs + tid * 16;
  const int a_off = (wm + l16) * 64 + ((quad ^ (l16 & 3)) * 16);
  const int b_off = (wn + l16) * 64 + ((quad ^ (l16 & 3)) * 16);

  f32x4 acc[4][4] = {};

  for (int k0 = 0; k0 < 1024; k0 += 32) {
    __syncthreads();
    gld16(ga + k0, lA);
    gld16(ga + k0 + 64 * 1024, lA + 4096);
    gld16(gb + k0, lB);
    gld16(gb + k0 + 64 * 1024, lB + 4096);
    __syncthreads();
    bf16x8 af[4], bfr[4];
#pragma unroll
    for (int mi = 0; mi < 4; ++mi)
      af[mi] = *(const bf16x8*)((const char*)As + a_off + mi * 1024);
#pragma unroll
    for (int ni = 0; ni < 4; ++ni)
      bfr[ni] = *(const bf16x8*)((const char*)Bs + b_off + ni * 1024);
#pragma unroll
    for (int mi = 0; mi < 4; ++mi)
#pragma unroll
      for (int ni = 0; ni < 4; ++ni)
        acc[mi][ni] = __builtin_amdgcn_mfma_f32_16x16x32_bf16(af[mi], bfr[ni],
                                                              acc[mi][ni], 0, 0, 0);
  }

  if (z < 2) {  // token-major -> [b][h][s][dk]
#pragma unroll
    for (int ni = 0; ni < 4; ++ni) {
      const int col = n0 + wn + ni * 16 + l16;
      const int h = col >> 6, dk = col & 63;
      const float bb = bias[col];
#pragma unroll
      for (int mi = 0; mi < 4; ++mi)
#pragma unroll
        for (int r = 0; r < 4; ++r) {
          const int row = m0 + wm + mi * 16 + quad * 4 + r;
          const int b = row >> 11, s = row & 2047;
          out[((size_t)(b * 16 + h) * 2048 + s) * 64 + dk] =
              (__bf16)((acc[mi][ni][r] + bb) * scale);
        }
    }
  } else {  // V: A=W (m=feature), B=X (n=token); store Vt[b][h][dk][s]
#pragma unroll
    for (int mi = 0; mi < 4; ++mi)
#pragma unroll
      for (int r = 0; r < 4; ++r) {
        const int rowm = m0 + wm + mi * 16 + quad * 4 + r;
        const int h = rowm >> 6, dk = rowm & 63;
        const float bb = bias[rowm];
#pragma unroll
        for (int ni = 0; ni < 4; ++ni) {
          const int coln = n0 + wn + ni * 16 + l16;
          const int b = coln >> 11, s = coln & 2047;
          out[((size_t)(b * 16 + h) * 64 + dk) * 2048 + s] =
              (__bf16)(acc[mi][ni][r] + bb);
        }
      }
  }
}

// ---------------- output projection GEMM (f32 out) ----------------
__global__ __launch_bounds__(256) void gemm_out(const __bf16* __restrict__ A,
                                                const __bf16* __restrict__ B,
                                                const float* __restrict__ bias,
                                                float* __restrict__ out) {
  __shared__ __align__(16) __bf16 As[128 * 32];
  __shared__ __align__(16) __bf16 Bs[128 * 32];
  const int tid = threadIdx.x;
  const int m0 = blockIdx.y * 128;
  const int n0 = blockIdx.x * 128;
  const int lane = tid & 63, wid = tid >> 6;
  const int wm = (wid & 1) * 64, wn = (wid >> 1) * 64;
  const int l16 = lane & 15, quad = lane >> 4;

  const int sc = (tid & 3) ^ ((tid >> 2) & 3);
  const __bf16* ga = A + (size_t)(m0 + (tid >> 2)) * 1024 + sc * 8;
  const __bf16* gb = B + (size_t)(n0 + (tid >> 2)) * 1024 + sc * 8;
  char* lA = (char*)As + tid * 16;
  char* lB = (char*)Bs + tid * 16;
  const int a_off = (wm + l16) * 64 + ((quad ^ (l16 & 3)) * 16);
  const int b_off = (wn + l16) * 64 + ((quad ^ (l16 & 3)) * 16);

  f32x4 acc[4][4] = {};

  for (int k0 = 0; k0 < 1024; k0 += 32) {
    __syncthreads();
    gld16(ga + k0, lA);
    gld16(ga + k0 + 64 * 1024, lA + 4096);
    gld16(gb + k0, lB);
    gld16(gb + k0 + 64 * 1024, lB + 4096);
    __syncthreads();
    bf16x8 af[4], bfr[4];
#pragma unroll
    for (int mi = 0; mi < 4; ++mi)
      af[mi] = *(const bf16x8*)((const char*)As + a_off + mi * 1024);
#pragma unroll
    for (int ni = 0; ni < 4; ++ni)
      bfr[ni] = *(const bf16x8*)((const char*)Bs + b_off + ni * 1024);
#pragma unroll
    for (int mi = 0; mi < 4; ++mi)
#pragma unroll
      for (int ni = 0; ni < 4; ++ni)
        acc[mi][ni] = __builtin_amdgcn_mfma_f32_16x16x32_bf16(af[mi], bfr[ni],
                                                              acc[mi][ni], 0, 0, 0);
  }

#pragma unroll
  for (int ni = 0; ni < 4; ++ni) {
    const int col = n0 + wn + ni * 16 + l16;
    const float bb = bias[col];
#pragma unroll
    for (int mi = 0; mi < 4; ++mi)
#pragma unroll
      for (int r = 0; r < 4; ++r) {
        const int row = m0 + wm + mi * 16 + quad * 4 + r;
        out[(size_t)row * 1024 + col] = acc[mi][ni][r] + bb;
      }
  }
}

// ---------------- flash attention, dbuf K/V, exp2 softmax, f32 g ----------
// Qh,Kh: [b][h][s][64] bf16 (Q pre-scaled by QSCALE); Vt: [b][h][64][2048];
// gprob f32 [b][s][s]; out xb: [b][s][1024] bf16.
// K/V double-buffered: tile kt+1 prefetched at top of iteration kt -> loads
// are in flight for a whole iteration; ONE barrier per iteration.
__global__ __launch_bounds__(256) void attn_kernel(
    const __bf16* __restrict__ Qh, const __bf16* __restrict__ Kh,
    const __bf16* __restrict__ Vt, const float* __restrict__ gprob,
    const int* __restrict__ maskp, __bf16* __restrict__ xb) {
  __shared__ __align__(16) __bf16 Qs[64 * 64];
  __shared__ __align__(16) __bf16 Ks[2][64 * 64];
  __shared__ __align__(16) __bf16 Vs[2][64 * 64];  // Vt tile: [dk][s_rel]
  __shared__ __align__(16) __bf16 Ps[4][16 * 64];
  __shared__ unsigned long long mbits[32];

  const int tid = threadIdx.x;
  const int qt = blockIdx.x, bh = blockIdx.y;
  const int b = bh >> 4, h = bh & 15;
  const int q0 = qt * 64;
  const int lane = tid & 63, wid = tid >> 6, l16 = lane & 15, quad = lane >> 4;
  const size_t head_off = (size_t)bh * (2048 * 64);

  const int srow = tid >> 3;                 // staging row 0..31
  const int sc8 = (tid & 7) ^ (srow & 7);    // swizzled source chunk
  const int fxor = (l16 & 7);                // frag-read chunk xor

  const __bf16* gk0 = Kh + head_off + (size_t)srow * 64 + sc8 * 8;
  const __bf16* gv0 = Vt + head_off + (size_t)srow * 2048 + sc8 * 8;

  {  // prologue staging: Q tile + K/V tile 0 into buffer 0
    const __bf16* gq = Qh + head_off + (size_t)(q0 + srow) * 64 + sc8 * 8;
    gld16(gq, (char*)Qs + tid * 16);
    gld16(gq + 32 * 64, (char*)Qs + 4096 + tid * 16);
    gld16(gk0, (char*)Ks + tid * 16);
    gld16(gk0 + 2048, (char*)Ks + 4096 + tid * 16);
    gld16(gv0, (char*)Vs + tid * 16);
    gld16(gv0 + 32 * 2048, (char*)Vs + 4096 + tid * 16);
  }
  // one-time mask ballot: mbits[kt] bit j = mask[b][kt*64+j]
  {
    const int* mr = maskp + b * 2048;
#pragma unroll
    for (int t = 0; t < 8; ++t) {
      const int kt2 = wid * 8 + t;
      const int mv = mr[kt2 * 64 + lane];
      const unsigned long long bal = __ballot(mv != 0);
      if (lane == 0) mbits[kt2] = bal;
    }
  }
  __syncthreads();  // drains prologue staging (vmcnt0) + mbits visible
  bf16x8 aq[2];
  aq[0] = *(const bf16x8*)((const char*)Qs + (wid * 16 + l16) * 128 +
                           ((quad ^ fxor) * 16));
  aq[1] = *(const bf16x8*)((const char*)Qs + (wid * 16 + l16) * 128 +
                           (((4 + quad) ^ fxor) * 16));

  f32x4 o[4] = {};
  float lp[4] = {0.f, 0.f, 0.f, 0.f};
  int irow[4];
#pragma unroll
  for (int r = 0; r < 4; ++r) irow[r] = q0 + wid * 16 + quad * 4 + r;

  // g in A-frag layout: row q0+wid*16+l16, col chunk (kh*4+quad)*8
  const float* gpl = gprob + (size_t)b * 2048 * 2048 +
                     (size_t)(q0 + wid * 16 + l16) * 2048 + quad * 8;
  // g for tile 0 (consumed at kt=0 PV; in flight during QK+softmax)
  float4 g0 = *(const float4*)(gpl);
  float4 g1 = *(const float4*)(gpl + 4);
  float4 g2 = *(const float4*)(gpl + 32);
  float4 g3 = *(const float4*)(gpl + 36);

  for (int kt = 0; kt < 32; ++kt) {
    const int cur = kt & 1;
    float4 gn0, gn1, gn2, gn3;
    if (kt < 31) {  // prefetch K/V tile kt+1 into alternate buffer + g(kt+1)
      const int nb = cur ^ 1;
      gld16(gk0 + (kt + 1) * 4096, (char*)Ks + nb * 8192 + tid * 16);
      gld16(gk0 + (kt + 1) * 4096 + 2048, (char*)Ks + nb * 8192 + 4096 + tid * 16);
      gld16(gv0 + (kt + 1) * 64, (char*)Vs + nb * 8192 + tid * 16);
      gld16(gv0 + (kt + 1) * 64 + 32 * 2048, (char*)Vs + nb * 8192 + 4096 + tid * 16);
      const float* gn = gpl + (kt + 1) * 64;
      gn0 = *(const float4*)(gn);
      gn1 = *(const float4*)(gn + 4);
      gn2 = *(const float4*)(gn + 32);
      gn3 = *(const float4*)(gn + 36);
    }

    // mask bits for this k-tile (broadcast LDS read + bit tests)
    const unsigned long long sh = mbits[kt] >> l16;
    const uint32_t shlo = (uint32_t)sh, shhi = (uint32_t)(sh >> 32);
    const bool mk[4] = {(shlo & 1) != 0, (shlo & 0x10000u) != 0,
                        (shhi & 1) != 0, (shhi & 0x10000u) != 0};

    // QK^T on buffer cur (scores already in log2 domain via QSCALE)
    f32x4 sc[4] = {};
#pragma unroll
    for (int kh = 0; kh < 2; ++kh)
#pragma unroll
      for (int ni = 0; ni < 4; ++ni) {
        bf16x8 bk = *(const bf16x8*)((const char*)Ks + cur * 8192 +
                                     (ni * 16 + l16) * 128 +
                                     (((kh * 4 + quad) ^ fxor) * 16));
        sc[ni] = __builtin_amdgcn_mfma_f32_16x16x32_bf16(aq[kh], bk, sc[ni], 0, 0, 0);
      }

    // max-free softmax: p = 2^s (scores bounded), masked -> 0.
    float pw[4][4];
    if (kt != qt) {
#pragma unroll
      for (int ni = 0; ni < 4; ++ni)
#pragma unroll
        for (int r = 0; r < 4; ++r) {
          const float e = __builtin_exp2f(sc[ni][r]);
          const float p = mk[ni] ? e : 0.f;
          lp[r] += p;
          pw[ni][r] = p;
        }
    } else {  // diagonal tile: j==irow[r] <=> ni==wid && l16==quad*4+r
#pragma unroll
      for (int ni = 0; ni < 4; ++ni)
#pragma unroll
        for (int r = 0; r < 4; ++r) {
          const float e = __builtin_exp2f(sc[ni][r]);
          const bool diag = (ni == wid) && (l16 == quad * 4 + r);
          const float p = (mk[ni] || diag) ? e : 0.f;
          lp[r] += p;
          pw[ni][r] = p;
        }
    }

    // P (masked, un-g-scaled) -> per-wave LDS tile (C-layout -> A-layout)
#pragma unroll
    for (int ni = 0; ni < 4; ++ni)
#pragma unroll
      for (int r = 0; r < 4; ++r) {
        const int prow = quad * 4 + r;
        const int pchunk = (ni * 2 + (l16 >> 3)) ^ (prow & 7);
        *(__bf16*)((char*)&Ps[wid][0] + prow * 128 + pchunk * 16 + (l16 & 7) * 2) =
            (__bf16)pw[ni][r];
      }
    asm volatile("s_waitcnt lgkmcnt(0)" ::: "memory");  // wave-private write->read

    // O += (P .* g) @ V — g applied on the A-fragment (contiguous per lane)
    const float gfl[16] = {g0.x, g0.y, g0.z, g0.w, g1.x, g1.y, g1.z, g1.w,
                           g2.x, g2.y, g2.z, g2.w, g3.x, g3.y, g3.z, g3.w};
#pragma unroll
    for (int kh = 0; kh < 2; ++kh) {
      bf16x8 ap = *(const bf16x8*)((const char*)&Ps[wid][0] + l16 * 128 +
                                   (((kh * 4 + quad) ^ fxor) * 16));
      bf16x8 apg;
#pragma unroll
      for (int j = 0; j < 8; ++j)
        apg[j] = (__bf16)((float)ap[j] * gfl[kh * 8 + j]);
#pragma unroll
      for (int ni = 0; ni < 4; ++ni) {
        bf16x8 bv = *(const bf16x8*)((const char*)Vs + cur * 8192 +
                                     (ni * 16 + l16) * 128 +
                                     (((kh * 4 + quad) ^ fxor) * 16));
        o[ni] = __builtin_amdgcn_mfma_f32_16x16x32_bf16(apg, bv, o[ni], 0, 0, 0);
      }
    }

    if (kt < 31) { g0 = gn0; g1 = gn1; g2 = gn2; g3 = gn3; }
    __syncthreads();  // end of iter: prev readers done + prefetch drained
  }

  // reduce l across the 16 lanes holding each row, then write x = O / l
#pragma unroll
  for (int r = 0; r < 4; ++r) {
    lp[r] += __shfl_xor(lp[r], 1);
    lp[r] += __shfl_xor(lp[r], 2);
    lp[r] += __shfl_xor(lp[r], 4);
    lp[r] += __shfl_xor(lp[r], 8);
    lp[r] = 1.f / lp[r];
  }
#pragma unroll
  for (int ni = 0; ni < 4; ++ni) {
    const int dk = ni * 16 + l16;
#pragma unroll
    for (int r = 0; r < 4; ++r) {
      const float val = o[ni][r] * lp[r];
      xb[((size_t)(b * 2048 + irow[r])) * 1024 + h * 64 + dk] = (__bf16)val;
    }
  }
}

extern "C" void kernel_launch(void* const* d_in, const int* in_sizes, int n_in,
                              void* d_out, int out_size, void* d_ws, size_t ws_size,
                              hipStream_t stream) {
  const float* query = (const float*)d_in[0];
  const float* key_  = (const float*)d_in[1];
  const float* value = (const float*)d_in[2];
  const float* gprob = (const float*)d_in[3];
  const int*   maskp = (const int*)d_in[4];
  const float* Wq = (const float*)d_in[5];
  const float* bq = (const float*)d_in[6];
  const float* Wk = (const float*)d_in[7];
  const float* bk = (const float*)d_in[8];
  const float* Wv = (const float*)d_in[9];
  const float* bv = (const float*)d_in[10];
  const float* Wo = (const float*)d_in[11];
  const float* bo = (const float*)d_in[12];

  char* ws = (char*)d_ws;
  const size_t MB = 1 << 20;
  __bf16* qb  = (__bf16*)(ws + 0 * MB);
  __bf16* kb  = (__bf16*)(ws + 8 * MB);
  __bf16* vb  = (__bf16*)(ws + 16 * MB);
  __bf16* Wqb = (__bf16*)(ws + 24 * MB);
  __bf16* Wkb = (__bf16*)(ws + 26 * MB);
  __bf16* Wvb = (__bf16*)(ws + 28 * MB);
  __bf16* Wob = (__bf16*)(ws + 30 * MB);
  __bf16* Qh  = (__bf16*)(ws + 32 * MB);
  __bf16* Kh  = (__bf16*)(ws + 40 * MB);
  __bf16* Vt  = (__bf16*)(ws + 48 * MB);
  __bf16* xb  = (__bf16*)(ws + 56 * MB);

  CastArgs ca;
  ca.src[0] = query; ca.dst[0] = qb;  ca.n[0] = 4194304;
  ca.src[1] = key_;  ca.dst[1] = kb;  ca.n[1] = 4194304;
  ca.src[2] = value; ca.dst[2] = vb;  ca.n[2] = 4194304;
  ca.src[3] = Wq;    ca.dst[3] = Wqb; ca.n[3] = 1048576;
  ca.src[4] = Wk;    ca.dst[4] = Wkb; ca.n[4] = 1048576;
  ca.src[5] = Wv;    ca.dst[5] = Wvb; ca.n[5] = 1048576;
  ca.src[6] = Wo;    ca.dst[6] = Wob; ca.n[6] = 1048576;
  cast_bf16_kernel<<<dim3(2048, 7), 256, 0, stream>>>(ca);

  QkvArgs qa;
  qa.A[0] = qb;  qa.B[0] = Wqb; qa.bias[0] = bq; qa.out[0] = Qh;
  qa.A[1] = kb;  qa.B[1] = Wkb; qa.bias[1] = bk; qa.out[1] = Kh;
  qa.A[2] = Wvb; qa.B[2] = vb;  qa.bias[2] = bv; qa.out[2] = Vt;
  qkv_gemm<<<dim3(256, 3), 256, 0, stream>>>(qa);

  attn_kernel<<<dim3(32, 32), 256, 0, stream>>>(Qh, Kh, Vt, gprob, maskp, xb);
  gemm_out<<<dim3(8, 32), 256, 0, stream>>>(xb, Wob, bo, (float*)d_out);
}